// Round 1
// baseline (3913.889 us; speedup 1.0000x reference)
//
#include <hip/hip_runtime.h>
#include <cstdint>

#define B 2048
#define NL 32
#define FEAT 512
#define HID 512
#define HW 64
#define OUTSZ 42
#define G3 1536   // 3*HID
#define SSP 48    // padded ss width (42 -> 48, cols 42..47 stay zero)
#define LDIH 554  // gru_w_ih row stride

// ---- one-time weight re-pack: W_ih[:, :512] -> dense, W_ih[:, 512:554] -> padded 48 ----
__global__ __launch_bounds__(256) void prep_kernel(const float* __restrict__ w_ih,
                                                   float* __restrict__ w_ih512,
                                                   float* __restrict__ w_ss_pad){
  int idx = blockIdx.x*256 + threadIdx.x;
  if (idx < G3*512){
    int r = idx >> 9, c = idx & 511;
    w_ih512[idx] = w_ih[r*LDIH + c];
  } else {
    int i2 = idx - G3*512;
    if (i2 < G3*SSP){
      int r = i2 / SSP, c = i2 % SSP;
      w_ss_pad[i2] = (c < OUTSZ) ? w_ih[r*LDIH + 512 + c] : 0.f;
    }
  }
}

// ---- attention precompute (step-invariant: softmax is shift-invariant) ----
__global__ __launch_bounds__(256) void att_kernel(const float* __restrict__ feat,
                                                  const float* __restrict__ att_w,
                                                  float* __restrict__ att_feat){
  int b = blockIdx.x;
  const float* fb = feat + (size_t)b * FEAT * HW;
  __shared__ float part[4][64];
  __shared__ float attv[64];
  int t = threadIdx.x;
  int s = t & 63, q = t >> 6;
  float acc = 0.f;
  for (int c = q*128; c < q*128 + 128; ++c)
    acc = fmaf(fb[c*HW + s], att_w[c], acc);
  part[q][s] = acc;
  __syncthreads();
  if (t < 64){
    float v = part[0][t] + part[1][t] + part[2][t] + part[3][t];
    float m = v;
    for (int o = 32; o > 0; o >>= 1) m = fmaxf(m, __shfl_xor(m, o));
    float e = __expf(v - m);
    float ssum = e;
    for (int o = 32; o > 0; o >>= 1) ssum += __shfl_xor(ssum, o);
    attv[t] = e / ssum * 2.0f;   // * BETA
  }
  __syncthreads();
  for (int c = t; c < FEAT; c += 256){
    const float4* row = (const float4*)(fb + c*HW);
    float a2 = 0.f;
    #pragma unroll
    for (int k = 0; k < 16; ++k){
      float4 v4 = row[k];
      a2 = fmaf(v4.x, attv[k*4+0], a2);
      a2 = fmaf(v4.y, attv[k*4+1], a2);
      a2 = fmaf(v4.z, attv[k*4+2], a2);
      a2 = fmaf(v4.w, attv[k*4+3], a2);
    }
    att_feat[(size_t)b*FEAT + c] = a2;
  }
}

// ---- tiled fp32 GEMM:  C[M,N] = act( A[M,K] * Bw[N,K]^T + bias )  (NT, dot of rows) ----
template<int ACT>
__global__ __launch_bounds__(256) void gemm_nt(const float* __restrict__ A,
                                               const float* __restrict__ Bw,
                                               const float* __restrict__ bias,
                                               float* __restrict__ C,
                                               int K, int lda, int ldb, int ldc){
  __shared__ __align__(16) float As[16][68];
  __shared__ __align__(16) float Bs[16][68];
  const int tid = threadIdx.x;
  const int m0 = blockIdx.y*64, n0 = blockIdx.x*64;
  const int tm = tid >> 4, tn = tid & 15;
  const int lr = tid >> 2, lk = (tid & 3)*4;
  float acc[4][4] = {};
  const float* Aptr = A + (size_t)(m0 + lr)*lda + lk;
  const float* Bptr = Bw + (size_t)(n0 + lr)*ldb + lk;
  for (int k0 = 0; k0 < K; k0 += 16){
    float4 av = *(const float4*)(Aptr + k0);
    float4 bv = *(const float4*)(Bptr + k0);
    __syncthreads();
    As[lk+0][lr]=av.x; As[lk+1][lr]=av.y; As[lk+2][lr]=av.z; As[lk+3][lr]=av.w;
    Bs[lk+0][lr]=bv.x; Bs[lk+1][lr]=bv.y; Bs[lk+2][lr]=bv.z; Bs[lk+3][lr]=bv.w;
    __syncthreads();
#pragma unroll
    for (int kk = 0; kk < 16; ++kk){
      float4 a4 = *(const float4*)&As[kk][tm*4];
      float4 b4 = *(const float4*)&Bs[kk][tn*4];
      float a[4] = {a4.x, a4.y, a4.z, a4.w};
      float bb[4] = {b4.x, b4.y, b4.z, b4.w};
#pragma unroll
      for (int i = 0; i < 4; ++i)
#pragma unroll
        for (int j = 0; j < 4; ++j)
          acc[i][j] = fmaf(a[i], bb[j], acc[i][j]);
    }
  }
  float bx[4] = {0.f, 0.f, 0.f, 0.f};
  if (bias){
    bx[0]=bias[n0+tn*4+0]; bx[1]=bias[n0+tn*4+1];
    bx[2]=bias[n0+tn*4+2]; bx[3]=bias[n0+tn*4+3];
  }
#pragma unroll
  for (int i = 0; i < 4; ++i){
    float4 o;
    o.x = acc[i][0]+bx[0]; o.y = acc[i][1]+bx[1];
    o.z = acc[i][2]+bx[2]; o.w = acc[i][3]+bx[3];
    if (ACT){ o.x=fmaxf(o.x,0.f); o.y=fmaxf(o.y,0.f); o.z=fmaxf(o.z,0.f); o.w=fmaxf(o.w,0.f); }
    *(float4*)(C + (size_t)(m0 + tm*4 + i)*ldc + n0 + tn*4) = o;
  }
}

// ---- GRU gates (elementwise) ----
__global__ __launch_bounds__(512) void gates_kernel(const float* __restrict__ gi_base,
                                                    const float* __restrict__ gi_ss,
                                                    const float* __restrict__ gh,
                                                    float* __restrict__ h,
                                                    float* __restrict__ hrelu){
  int b = blockIdx.x, j = threadIdx.x;
  size_t o3 = (size_t)b*G3 + j;
  float ir = gi_base[o3]        + gi_ss[o3];
  float iz = gi_base[o3 + 512]  + gi_ss[o3 + 512];
  float in = gi_base[o3 + 1024] + gi_ss[o3 + 1024];
  float hr = gh[o3], hz = gh[o3 + 512], hn = gh[o3 + 1024];
  float r = 1.f / (1.f + __expf(-(ir + hr)));
  float z = 1.f / (1.f + __expf(-(iz + hz)));
  float n = tanhf(in + r*hn);
  size_t oh = (size_t)b*HID + j;
  float hv = (1.f - z)*n + z*h[oh];
  h[oh] = hv;
  hrelu[oh] = fmaxf(hv, 0.f);
}

// ---- lin2 + outputs (point_pos, line softmax) + build ss for step t+1 ----
__global__ __launch_bounds__(64) void out_kernel(const float* __restrict__ o1relu,
                                                 const float* __restrict__ lin2_w,
                                                 const float* __restrict__ lin2_b,
                                                 const float* __restrict__ gt,
                                                 const int* __restrict__ line_prob,
                                                 const float* __restrict__ sample_prob,
                                                 float* __restrict__ out,
                                                 float* __restrict__ ss,
                                                 int t){
  int b = blockIdx.x, j = threadIdx.x;
  __shared__ __align__(16) float xr[512];
  __shared__ float pair[2];
  const float4* src = (const float4*)(o1relu + (size_t)b*512);
  float4* dst4 = (float4*)xr;
  for (int i = j; i < 128; i += 64) dst4[i] = src[i];
  __syncthreads();
  float acc = 0.f;
  if (j < OUTSZ){
    acc = lin2_b[j];
    const float4* wr = (const float4*)(lin2_w + (size_t)j*512);
    #pragma unroll 8
    for (int k = 0; k < 128; ++k){
      float4 w = wr[k];
      float4 x = *(const float4*)&xr[k*4];
      acc = fmaf(w.x, x.x, acc);
      acc = fmaf(w.y, x.y, acc);
      acc = fmaf(w.z, x.z, acc);
      acc = fmaf(w.w, x.w, acc);
    }
    if (j < 40) out[((size_t)b*NL + t)*40 + j] = acc;
    else        pair[j - 40] = acc;
  }
  __syncthreads();
  if (j == 0){
    float a = pair[0], c = pair[1];
    float m = fmaxf(a, c);
    float e0 = __expf(a - m), e1 = __expf(c - m);
    float s = e0 + e1;
    size_t base = (size_t)B*NL*40 + ((size_t)b*NL + t)*2;
    out[base]     = e0 / s;
    out[base + 1] = e1 / s;
  }
  // build ss for step t+1:  ss = use_prev ? o_t : gt_{t+1}
  if (t + 1 < NL && j < OUTSZ){
    bool up = sample_prob[(size_t)(t+1)*B + b] < 0.1f;
    float gtv;
    if (j < 40) gtv = gt[((size_t)b*NL + t)*40 + j];
    else {
      float pv = (float)line_prob[b*NL + t];
      gtv = (j == 40) ? 1.f - pv : pv;
    }
    ss[(size_t)b*SSP + j] = up ? acc : gtv;
  }
}

extern "C" void kernel_launch(void* const* d_in, const int* in_sizes, int n_in,
                              void* d_out, int out_size, void* d_ws, size_t ws_size,
                              hipStream_t stream) {
  const float* img         = (const float*)d_in[0];
  const float* gt          = (const float*)d_in[1];
  const int*   line_prob   = (const int*)d_in[2];
  const float* sample_prob = (const float*)d_in[3];
  const float* att_w       = (const float*)d_in[4];
  // d_in[5] att_b: unused — softmax is shift-invariant, att_b cancels
  const float* w_ih        = (const float*)d_in[6];
  const float* w_hh        = (const float*)d_in[7];
  const float* b_ih        = (const float*)d_in[8];
  const float* b_hh        = (const float*)d_in[9];
  const float* lin1_w      = (const float*)d_in[10];
  const float* lin1_b      = (const float*)d_in[11];
  const float* lin2_w      = (const float*)d_in[12];
  const float* lin2_b      = (const float*)d_in[13];
  float* out = (float*)d_out;

  float* p = (float*)d_ws;
  float* att_feat = p;  p += (size_t)B*FEAT;
  float* gi_base  = p;  p += (size_t)B*G3;
  float* gi_ss    = p;  p += (size_t)B*G3;
  float* gh       = p;  p += (size_t)B*G3;
  float* h        = p;  p += (size_t)B*HID;
  float* hrelu    = p;  p += (size_t)B*HID;
  float* o1       = p;  p += (size_t)B*512;
  float* ss       = p;  p += (size_t)B*SSP;
  float* w_ih512  = p;  p += (size_t)G3*512;
  float* w_ss_pad = p;  p += (size_t)G3*SSP;

  hipMemsetAsync(h,  0, (size_t)B*HID*sizeof(float), stream);
  hipMemsetAsync(ss, 0, (size_t)B*SSP*sizeof(float), stream);

  int prep_n = G3*512 + G3*SSP;
  prep_kernel<<<(prep_n + 255)/256, 256, 0, stream>>>(w_ih, w_ih512, w_ss_pad);
  att_kernel<<<B, 256, 0, stream>>>(img, att_w, att_feat);

  // gi_base = att_feat @ W_ih[:, :512]^T + b_ih   (step-invariant)
  gemm_nt<0><<<dim3(G3/64, B/64), 256, 0, stream>>>(att_feat, w_ih512, b_ih, gi_base,
                                                    512, 512, 512, G3);
  for (int t = 0; t < NL; ++t){
    // gh = h @ W_hh^T + b_hh
    gemm_nt<0><<<dim3(G3/64, B/64), 256, 0, stream>>>(h, w_hh, b_hh, gh,
                                                      512, 512, 512, G3);
    // gi_ss = ss @ W_ss^T (padded K=48, pad cols are zero on both sides)
    gemm_nt<0><<<dim3(G3/64, B/64), 256, 0, stream>>>(ss, w_ss_pad, nullptr, gi_ss,
                                                      SSP, SSP, SSP, G3);
    gates_kernel<<<B, 512, 0, stream>>>(gi_base, gi_ss, gh, h, hrelu);
    // o1 = relu(relu(h) @ lin1_w^T + lin1_b)
    gemm_nt<1><<<dim3(512/64, B/64), 256, 0, stream>>>(hrelu, lin1_w, lin1_b, o1,
                                                       512, 512, 512, 512);
    out_kernel<<<B, 64, 0, stream>>>(o1, lin2_w, lin2_b, gt, line_prob, sample_prob,
                                     out, ss, t);
  }
}

// Round 3
// 3589.708 us; speedup vs baseline: 1.0903x; 1.0903x over previous
//
#include <hip/hip_runtime.h>
#include <hip/hip_bf16.h>
#include <cstdint>

#define B 2048
#define NL 32
#define FEAT 512
#define HID 512
#define HW 64
#define OUTSZ 42
#define G3 1536    // 3*HID
#define KC 576     // padded combined K: 512 (h) + 42 (ss) -> 576
#define LDIH 554   // gru_w_ih row stride

typedef __bf16 bf16x8 __attribute__((ext_vector_type(8)));
typedef float f32x4 __attribute__((ext_vector_type(4)));
typedef __hip_bfloat16 bf16_t;

// ---- one-time weight conversion/re-pack to bf16 ----
// w_comb  [G3][KC]  : cols 0..511 = w_hh; cols 512..553 = w_ih[:,512:554] for
//                     r/z gate rows (r<1024) ONLY, zero for n-gate rows; rest 0
// w_ih512 [G3][512] : w_ih[:, :512]
// lin1_wb [512][512]
__global__ __launch_bounds__(256) void prep_kernel(const float* __restrict__ w_ih,
                                                   const float* __restrict__ w_hh,
                                                   const float* __restrict__ lin1_w,
                                                   bf16_t* __restrict__ w_comb,
                                                   bf16_t* __restrict__ w_ih512,
                                                   bf16_t* __restrict__ lin1_wb){
  const int N1 = G3*KC, N2 = G3*512, N3 = 512*512;
  for (int idx = blockIdx.x*256 + threadIdx.x; idx < N1 + N2 + N3; idx += gridDim.x*256){
    if (idx < N1){
      int r = idx / KC, c = idx % KC;
      float v = (c < 512) ? w_hh[r*512 + c]
              : ((c < 512 + OUTSZ && r < 1024) ? w_ih[r*LDIH + c] : 0.f);
      w_comb[idx] = __float2bfloat16(v);
    } else if (idx < N1 + N2){
      int i2 = idx - N1;
      int r = i2 >> 9, c = i2 & 511;
      w_ih512[i2] = __float2bfloat16(w_ih[r*LDIH + c]);
    } else {
      int i3 = idx - N1 - N2;
      lin1_wb[i3] = __float2bfloat16(lin1_w[i3]);
    }
  }
}

// ---- attention precompute (step-invariant: softmax is shift-invariant) ----
__global__ __launch_bounds__(256) void att_kernel(const float* __restrict__ feat,
                                                  const float* __restrict__ att_w,
                                                  bf16_t* __restrict__ att_feat){
  int b = blockIdx.x;
  const float* fb = feat + (size_t)b * FEAT * HW;
  __shared__ float part[4][64];
  __shared__ float attv[64];
  int t = threadIdx.x;
  int s = t & 63, q = t >> 6;
  float acc = 0.f;
  for (int c = q*128; c < q*128 + 128; ++c)
    acc = fmaf(fb[c*HW + s], att_w[c], acc);
  part[q][s] = acc;
  __syncthreads();
  if (t < 64){
    float v = part[0][t] + part[1][t] + part[2][t] + part[3][t];
    float m = v;
    for (int o = 32; o > 0; o >>= 1) m = fmaxf(m, __shfl_xor(m, o));
    float e = __expf(v - m);
    float ssum = e;
    for (int o = 32; o > 0; o >>= 1) ssum += __shfl_xor(ssum, o);
    attv[t] = e / ssum * 2.0f;   // * BETA
  }
  __syncthreads();
  for (int c = t; c < FEAT; c += 256){
    const float4* row = (const float4*)(fb + c*HW);
    float a2 = 0.f;
    #pragma unroll
    for (int k = 0; k < 16; ++k){
      float4 v4 = row[k];
      a2 = fmaf(v4.x, attv[k*4+0], a2);
      a2 = fmaf(v4.y, attv[k*4+1], a2);
      a2 = fmaf(v4.z, attv[k*4+2], a2);
      a2 = fmaf(v4.w, attv[k*4+3], a2);
    }
    att_feat[(size_t)b*FEAT + c] = __float2bfloat16(a2);
  }
}

// ---- bf16 MFMA GEMM (NT): C[M,N] = act( A[M,K] * W[N,K]^T + bias ) ----
// 64x64 block tile, 4 waves, each wave computes 64(M) x 16(N).
// Direct global loads (operands are L2-resident), no LDS.
template<int ACT>
__global__ __launch_bounds__(256) void gemm_mfma(const bf16_t* __restrict__ A,
                                                 const bf16_t* __restrict__ W,
                                                 const float* __restrict__ bias,
                                                 float* __restrict__ C,
                                                 int K, int lda, int ldw, int ldc){
  const int tid = threadIdx.x;
  const int w = tid >> 6, lane = tid & 63;
  const int r = lane & 15, half = lane >> 4;
  const int m_base = blockIdx.y * 64;
  const int n_base = blockIdx.x * 64 + w * 16;
  const bf16_t* Ap = A + (size_t)(m_base + r)*lda + half*8;
  const bf16_t* Wp = W + (size_t)(n_base + r)*ldw + half*8;
  f32x4 acc[4] = {};
  for (int k0 = 0; k0 < K; k0 += 32){
    bf16x8 bfrag = *(const bf16x8*)(Wp + k0);
    #pragma unroll
    for (int i = 0; i < 4; ++i){
      bf16x8 afrag = *(const bf16x8*)(Ap + (size_t)i*16*lda + k0);
      acc[i] = __builtin_amdgcn_mfma_f32_16x16x32_bf16(afrag, bfrag, acc[i], 0, 0, 0);
    }
  }
  const float bv = bias ? bias[n_base + r] : 0.f;
  #pragma unroll
  for (int i = 0; i < 4; ++i){
    #pragma unroll
    for (int q = 0; q < 4; ++q){
      float v = acc[i][q] + bv;
      if (ACT) v = fmaxf(v, 0.f);
      // D layout: col = lane&15 (= n offset r), row = (lane>>4)*4 + q
      C[(size_t)(m_base + i*16 + half*4 + q)*ldc + n_base + r] = v;
    }
  }
}

// ---- GRU gates ----
// ghss = [h|ss] @ w_comb^T + b_hh. For r/z rows this is gh + gi_ss; for the
// n rows (1024..1535) the ss columns of w_comb are zero, so ghss_n = gh_n = hn.
// gi_ssn supplies the input-side ss contribution to the n gate separately.
__global__ __launch_bounds__(512) void gates2_kernel(const float* __restrict__ gi_base,
                                                     const float* __restrict__ gi_ssn,
                                                     const float* __restrict__ ghss,
                                                     float* __restrict__ h,
                                                     bf16_t* __restrict__ xcomb,
                                                     bf16_t* __restrict__ hrelu_bf){
  int b = blockIdx.x, j = threadIdx.x;
  size_t o3 = (size_t)b*G3 + j;
  float ir = gi_base[o3]        + ghss[o3];                    // gi_r + gh_r + gi_ss_r
  float iz = gi_base[o3 + 512]  + ghss[o3 + 512];              // gi_z + gh_z + gi_ss_z
  float gin = gi_base[o3 + 1024] + gi_ssn[(size_t)b*512 + j];  // input-side n
  float hn  = ghss[o3 + 1024];                                 // hidden-side n
  float r = 1.f / (1.f + __expf(-ir));
  float z = 1.f / (1.f + __expf(-iz));
  float n = tanhf(gin + r*hn);
  size_t oh = (size_t)b*HID + j;
  float hv = (1.f - z)*n + z*h[oh];
  h[oh] = hv;
  xcomb[(size_t)b*KC + j] = __float2bfloat16(hv);
  hrelu_bf[oh] = __float2bfloat16(fmaxf(hv, 0.f));
}

// ---- small fp32 GEMV batch: gi_ssn[b][j] = ss[b] . w_ih[1024+j, 512:554] ----
__global__ __launch_bounds__(512) void ssn_kernel(const float* __restrict__ ssf,
                                                  const float* __restrict__ w_ih,
                                                  float* __restrict__ gi_ssn){
  int b = blockIdx.x, j = threadIdx.x;
  __shared__ float ssl[OUTSZ];
  if (j < OUTSZ) ssl[j] = ssf[(size_t)b*OUTSZ + j];
  __syncthreads();
  const float* wr = w_ih + (size_t)(1024 + j)*LDIH + 512;
  float acc = 0.f;
  #pragma unroll
  for (int k = 0; k < OUTSZ; ++k) acc = fmaf(wr[k], ssl[k], acc);
  gi_ssn[(size_t)b*512 + j] = acc;
}

// ---- lin2 + outputs (point_pos, line softmax) + build ss for step t+1 ----
__global__ __launch_bounds__(64) void out_kernel(const float* __restrict__ o1relu,
                                                 const float* __restrict__ lin2_w,
                                                 const float* __restrict__ lin2_b,
                                                 const float* __restrict__ gt,
                                                 const int* __restrict__ line_prob,
                                                 const float* __restrict__ sample_prob,
                                                 float* __restrict__ out,
                                                 bf16_t* __restrict__ xcomb,
                                                 float* __restrict__ ssf,
                                                 int t){
  int b = blockIdx.x, j = threadIdx.x;
  __shared__ __align__(16) float xr[512];
  __shared__ float pair[2];
  const float4* src = (const float4*)(o1relu + (size_t)b*512);
  float4* dst4 = (float4*)xr;
  for (int i = j; i < 128; i += 64) dst4[i] = src[i];
  __syncthreads();
  float acc = 0.f;
  if (j < OUTSZ){
    acc = lin2_b[j];
    const float4* wr = (const float4*)(lin2_w + (size_t)j*512);
    #pragma unroll 8
    for (int k = 0; k < 128; ++k){
      float4 wv = wr[k];
      float4 x = *(const float4*)&xr[k*4];
      acc = fmaf(wv.x, x.x, acc);
      acc = fmaf(wv.y, x.y, acc);
      acc = fmaf(wv.z, x.z, acc);
      acc = fmaf(wv.w, x.w, acc);
    }
    if (j < 40) out[((size_t)b*NL + t)*40 + j] = acc;
    else        pair[j - 40] = acc;
  }
  __syncthreads();
  if (j == 0){
    float a = pair[0], c = pair[1];
    float m = fmaxf(a, c);
    float e0 = __expf(a - m), e1 = __expf(c - m);
    float s = e0 + e1;
    size_t base = (size_t)B*NL*40 + ((size_t)b*NL + t)*2;
    out[base]     = e0 / s;
    out[base + 1] = e1 / s;
  }
  // build ss for step t+1:  ss = use_prev ? o_t : gt_{t+1}
  if (t + 1 < NL && j < OUTSZ){
    bool up = sample_prob[(size_t)(t+1)*B + b] < 0.1f;
    float gtv;
    if (j < 40) gtv = gt[((size_t)b*NL + t)*40 + j];
    else {
      float pv = (float)line_prob[b*NL + t];
      gtv = (j == 40) ? 1.f - pv : pv;
    }
    float sv = up ? acc : gtv;
    xcomb[(size_t)b*KC + 512 + j] = __float2bfloat16(sv);
    ssf[(size_t)b*OUTSZ + j] = sv;
  }
}

extern "C" void kernel_launch(void* const* d_in, const int* in_sizes, int n_in,
                              void* d_out, int out_size, void* d_ws, size_t ws_size,
                              hipStream_t stream) {
  const float* img         = (const float*)d_in[0];
  const float* gt          = (const float*)d_in[1];
  const int*   line_prob   = (const int*)d_in[2];
  const float* sample_prob = (const float*)d_in[3];
  const float* att_w       = (const float*)d_in[4];
  // d_in[5] att_b: unused — softmax is shift-invariant, att_b cancels
  const float* w_ih        = (const float*)d_in[6];
  const float* w_hh        = (const float*)d_in[7];
  const float* b_ih        = (const float*)d_in[8];
  const float* b_hh        = (const float*)d_in[9];
  const float* lin1_w      = (const float*)d_in[10];
  const float* lin1_b      = (const float*)d_in[11];
  const float* lin2_w      = (const float*)d_in[12];
  const float* lin2_b      = (const float*)d_in[13];
  float* out = (float*)d_out;

  char* p = (char*)d_ws;
  auto alloc = [&](size_t bytes){ void* q = p; p += (bytes + 255) & ~(size_t)255; return q; };
  float*  gi_base  = (float*)alloc((size_t)B*G3*4);
  float*  ghss     = (float*)alloc((size_t)B*G3*4);
  float*  gi_ssn   = (float*)alloc((size_t)B*512*4);
  float*  h        = (float*)alloc((size_t)B*HID*4);
  float*  o1       = (float*)alloc((size_t)B*512*4);
  float*  ssf      = (float*)alloc((size_t)B*OUTSZ*4);
  bf16_t* xcomb    = (bf16_t*)alloc((size_t)B*KC*2);
  bf16_t* hrelu_bf = (bf16_t*)alloc((size_t)B*512*2);
  bf16_t* att_bf   = (bf16_t*)alloc((size_t)B*FEAT*2);
  bf16_t* w_comb   = (bf16_t*)alloc((size_t)G3*KC*2);
  bf16_t* w_ih512b = (bf16_t*)alloc((size_t)G3*512*2);
  bf16_t* lin1_wb  = (bf16_t*)alloc((size_t)512*512*2);

  hipMemsetAsync(h,     0, (size_t)B*HID*4, stream);
  hipMemsetAsync(xcomb, 0, (size_t)B*KC*2, stream);
  hipMemsetAsync(ssf,   0, (size_t)B*OUTSZ*4, stream);

  prep_kernel<<<2048, 256, 0, stream>>>(w_ih, w_hh, lin1_w, w_comb, w_ih512b, lin1_wb);
  att_kernel<<<B, 256, 0, stream>>>(img, att_w, att_bf);

  // gi_base = att_feat @ W_ih[:, :512]^T + b_ih   (step-invariant)
  gemm_mfma<0><<<dim3(G3/64, B/64), 256, 0, stream>>>(att_bf, w_ih512b, b_ih, gi_base,
                                                      512, 512, 512, G3);
  for (int t = 0; t < NL; ++t){
    // ghss = [h|ss] @ [W_hh|W_ss(r,z)]^T + b_hh
    gemm_mfma<0><<<dim3(G3/64, B/64), 256, 0, stream>>>(xcomb, w_comb, b_hh, ghss,
                                                        KC, KC, KC, G3);
    // gi_ssn = ss @ W_ih_n_ss^T (input-side ss contribution to the n gate)
    ssn_kernel<<<B, 512, 0, stream>>>(ssf, w_ih, gi_ssn);
    gates2_kernel<<<B, 512, 0, stream>>>(gi_base, gi_ssn, ghss, h, xcomb, hrelu_bf);
    // o1 = relu(relu(h) @ lin1_w^T + lin1_b)
    gemm_mfma<1><<<dim3(512/64, B/64), 256, 0, stream>>>(hrelu_bf, lin1_wb, lin1_b, o1,
                                                         512, 512, 512, 512);
    out_kernel<<<B, 64, 0, stream>>>(o1, lin2_w, lin2_b, gt, line_prob, sample_prob,
                                     out, xcomb, ssf, t);
  }
}